// Round 8
// baseline (176.941 us; speedup 1.0000x reference)
//
#include <hip/hip_runtime.h>
#include <hip/hip_bf16.h>

#define N_NODES 50000
#define N_EDGES 800000
#define TOT_E   (N_EDGES + N_NODES)   // edges + self loops = 850000
#define NEG_SLOPE 0.2f
#define NBKT 196         // buckets of 256 nodes: 196*256 = 50176 >= 50000
#define NPB 256          // nodes per bucket
#define BKT_CAP 6144     // max edges per bucket (mean 4352, sd ~64)
#define CHUNK 4096       // edges per block in pass A
#define NCHUNK ((TOT_E + CHUNK - 1) / CHUNK)   // 208

typedef __attribute__((ext_vector_type(8))) short bf16x8;
typedef __attribute__((ext_vector_type(4))) float f32x4;
typedef __attribute__((ext_vector_type(2))) float f32x2;
typedef __attribute__((ext_vector_type(2))) _Float16 h2v;

static __device__ __forceinline__ unsigned short f2bf(float f) {
    unsigned int u = __float_as_uint(f);
    unsigned int r = (u + 0x7FFFu + ((u >> 16) & 1u)) >> 16;   // RNE
    return (unsigned short)r;
}
static __device__ __forceinline__ float bf2f(unsigned short h) {
    return __uint_as_float(((unsigned int)h) << 16);
}
static __device__ __forceinline__ unsigned short f2h(float f) {
    _Float16 h = (_Float16)f;                                   // v_cvt_f16_f32 (RNE)
    return __builtin_bit_cast(unsigned short, h);
}

// ---------------------------------------------------------------- CSR build
// Pass A: per-block LDS bucket counting-sort; blocks reserve space directly in
// fixed-capacity bucket regions of ebuf (one global atomic per block-bucket).
// packed u32: src[0:16) | local_dst[16:24) | bucket[24:32)
__global__ __launch_bounds__(1024) void kA(const int* __restrict__ srcp,
                                           const int* __restrict__ dstp,
                                           int* __restrict__ bcount,
                                           unsigned* __restrict__ ebuf) {
    __shared__ int h[NBKT];
    __shared__ int lbase[NBKT];
    __shared__ int lcur[NBKT];
    __shared__ int sc[256];
    __shared__ unsigned stage[CHUNK];
    int t = threadIdx.x;
    if (t < NBKT) h[t] = 0;
    __syncthreads();
    int base = blockIdx.x * CHUNK;
    int nloc = min(CHUNK, TOT_E - base);
    for (int i = t; i < nloc; i += 1024) {
        int e = base + i;
        int d = (e < N_EDGES) ? dstp[e] : (e - N_EDGES);
        atomicAdd(&h[d >> 8], 1);
    }
    __syncthreads();
    if (t < NBKT) lbase[t] = h[t] ? atomicAdd(&bcount[t], h[t]) : 0;
    if (t < 256) sc[t] = (t < NBKT) ? h[t] : 0;
    __syncthreads();
    for (int off = 1; off < 256; off <<= 1) {
        int v = (t < 256 && t >= off) ? sc[t - off] : 0;
        __syncthreads();
        if (t < 256) sc[t] += v;
        __syncthreads();
    }
    if (t < NBKT) lcur[t] = sc[t] - h[t];   // exclusive scan: run starts in stage
    __syncthreads();
    for (int i = t; i < nloc; i += 1024) {
        int e = base + i;
        int d = (e < N_EDGES) ? dstp[e] : (e - N_EDGES);
        int s = (e < N_EDGES) ? srcp[e] : (e - N_EDGES);
        int b = d >> 8;
        int p = atomicAdd(&lcur[b], 1);
        stage[p] = (unsigned)s | ((unsigned)(d & 255) << 16) | ((unsigned)b << 24);
    }
    __syncthreads();
    // stage is bucket-sorted: linear read -> contiguous runs into bucket regions
    for (int i = t; i < nloc; i += 1024) {
        unsigned v = stage[i];
        int b = v >> 24;
        int pl = lbase[b] + (i - (lcur[b] - h[b]));
        if (pl < BKT_CAP) ebuf[(size_t)b * BKT_CAP + pl] = v & 0xFFFFFFu;
    }
}

// scan bucket counts -> bbase (exclusive, NBKT+1 entries)
__global__ void kScanB(const int* __restrict__ bcount, int* __restrict__ bbase) {
    __shared__ int s[256];
    int t = threadIdx.x;   // 256 threads
    int own = (t < NBKT) ? bcount[t] : 0;
    s[t] = own;
    __syncthreads();
    for (int off = 1; off < 256; off <<= 1) {
        int v = (t >= off) ? s[t - off] : 0;
        __syncthreads();
        s[t] += v;
        __syncthreads();
    }
    if (t < NBKT) bbase[t] = s[t] - own;
    if (t == NBKT - 1) bbase[NBKT] = s[t];
}

// Pass B: one block per bucket -> exact CSR (rowptr + esrc), all coalesced
__global__ __launch_bounds__(1024) void kB(const unsigned* __restrict__ ebuf,
                                           const int* __restrict__ bcount,
                                           const int* __restrict__ bbase,
                                           int* __restrict__ rowptr,
                                           int* __restrict__ esrc) {
    __shared__ int h[NPB];
    __shared__ int sc[NPB];
    __shared__ int st2[BKT_CAP];
    int b = blockIdx.x;
    int t = threadIdx.x;
    int gb = bbase[b];
    int cnt = min(bcount[b], BKT_CAP);
    const unsigned* eb = ebuf + (size_t)b * BKT_CAP;
    if (t < NPB) h[t] = 0;
    __syncthreads();
    for (int i = t; i < cnt; i += 1024)
        atomicAdd(&h[(eb[i] >> 16) & 255], 1);
    __syncthreads();
    if (t < NPB) sc[t] = h[t];
    __syncthreads();
    for (int off = 1; off < NPB; off <<= 1) {
        int v = (t < NPB && t >= off) ? sc[t - off] : 0;
        __syncthreads();
        if (t < NPB) sc[t] += v;
        __syncthreads();
    }
    if (t < NPB) h[t] = sc[t] - h[t];   // exclusive scan (scatter cursor)
    __syncthreads();
    int node0 = b << 8;
    if (t < NPB && node0 + t < N_NODES) rowptr[node0 + t] = gb + h[t];
    if (b == NBKT - 1 && t == 0) rowptr[N_NODES] = TOT_E;
    for (int i = t; i < cnt; i += 1024) {
        unsigned v = eb[i];
        int p = atomicAdd(&h[(v >> 16) & 255], 1);
        st2[p] = (int)(v & 0xFFFFu);
    }
    __syncthreads();
    for (int i = t; i < cnt; i += 1024) esrc[gb + i] = st2[i];
}

// ------------------------------------------------- weight pack (both layers)
__global__ void k_pack2(const float* __restrict__ Wl1, const float* __restrict__ Wr1,
                        const float* __restrict__ Wl2, const float* __restrict__ Wr2,
                        unsigned short* __restrict__ Bp1, unsigned short* __restrict__ Bp2) {
    int gidx = blockIdx.x * 256 + threadIdx.x;   // 131072 total
    int which = gidx >> 16;
    int idx = gidx & 65535;
    const float* Wa = which ? Wl2 : Wl1;
    const float* Wb = which ? Wr2 : Wr1;
    unsigned short* Bp = which ? Bp2 : Bp1;
    int j = idx & 7, lane = (idx >> 3) & 63, t = idx >> 9;
    int ks = t >> 4, ctg = t & 15;
    int k = (ks * 32 + (lane >> 4) * 8 + j) & 127;
    int n = ctg * 16 + (lane & 15);
    float v = (n < 128) ? Wa[k * 128 + n] : Wb[k * 128 + (n - 128)];
    Bp[idx] = f2bf(v);
}

// ------------------------------------------------- MFMA dual linear -> fp16 out
template <bool F32IN>
__global__ __launch_bounds__(256) void k_mfma_lin(const void* __restrict__ Ain,
                                                  const unsigned short* __restrict__ Bp,
                                                  unsigned short* __restrict__ outA,
                                                  unsigned short* __restrict__ outB, int M) {
    __shared__ unsigned short lds_a[64][264];   // +8 pad
    int tid = threadIdx.x;
    int n0 = blockIdx.x * 64;
    if (F32IN) {
        const float* X = (const float*)Ain;
#pragma unroll
        for (int r = 0; r < 8; ++r) {
            int c = r * 256 + tid;
            int row = c >> 5;
            int col4 = (c & 31) * 4;
            int gr = n0 + row;
            if (gr >= M) gr = M - 1;
            float4 v = *(const float4*)&X[(size_t)gr * 128 + col4];
            float vv[4] = {v.x, v.y, v.z, v.w};
            ushort4 hh, ll;
            unsigned short* hp = &hh.x;
            unsigned short* lp = &ll.x;
#pragma unroll
            for (int q = 0; q < 4; ++q) {
                unsigned short hv = f2bf(vv[q]);
                hp[q] = hv;
                lp[q] = f2bf(vv[q] - bf2f(hv));
            }
            *(ushort4*)&lds_a[row][col4] = hh;
            *(ushort4*)&lds_a[row][128 + col4] = ll;
        }
    } else {
        const unsigned short* Ap = (const unsigned short*)Ain;
#pragma unroll
        for (int r = 0; r < 8; ++r) {
            int c = r * 256 + tid;
            int row = c >> 5;
            int col = (c & 31) * 8;
            int gr = n0 + row;
            if (gr >= M) gr = M - 1;
            float4 v = *(const float4*)&Ap[(size_t)gr * 256 + col];
            *(float4*)&lds_a[row][col] = v;
        }
    }
    __syncthreads();

    int w = tid >> 6, lane = tid & 63;
    int lrow = lane & 15, lhi = lane >> 4;
    f32x4 acc[4][4] = {};
    const bf16x8* Bf = (const bf16x8*)Bp;
#pragma unroll
    for (int ks = 0; ks < 8; ++ks) {
        bf16x8 bfr[4], afr[4];
#pragma unroll
        for (int ct = 0; ct < 4; ++ct)
            bfr[ct] = Bf[(ks * 16 + (w * 4 + ct)) * 64 + lane];
#pragma unroll
        for (int mt = 0; mt < 4; ++mt)
            afr[mt] = *(const bf16x8*)&lds_a[mt * 16 + lrow][ks * 32 + lhi * 8];
#pragma unroll
        for (int mt = 0; mt < 4; ++mt)
#pragma unroll
            for (int ct = 0; ct < 4; ++ct)
                acc[mt][ct] = __builtin_amdgcn_mfma_f32_16x16x32_bf16(
                    afr[mt], bfr[ct], acc[mt][ct], 0, 0, 0);
    }
#pragma unroll
    for (int mt = 0; mt < 4; ++mt) {
        int row0 = n0 + mt * 16 + lhi * 4;
#pragma unroll
        for (int ct = 0; ct < 4; ++ct) {
            int col = w * 64 + ct * 16 + lrow;
            unsigned short* dst = (col < 128) ? outA : outB;   // wave-uniform
            int cc = col & 127;
#pragma unroll
            for (int reg = 0; reg < 4; ++reg) {
                int rg = row0 + reg;
                if (rg < M) dst[(size_t)rg * 128 + cc] = f2h(acc[mt][ct][reg]);
            }
        }
    }
}

// ------------------------------------------------- fused score+softmax+aggregate
// One wave per node; 16 lanes per edge slot, 4 edge slots per wave.
// All elementwise math in f32x2 (v_pk_*_f32). Wave-uniform defer-max fast
// path: most batches skip the corr-rescale entirely (exact: corr==1 there).
template <int H, bool BF16OUT>
__global__ __launch_bounds__(256) void k_gat(const int* __restrict__ rowptr,
                                             const int* __restrict__ esrc,
                                             const unsigned short* __restrict__ xlh,
                                             const unsigned short* __restrict__ xrh,
                                             const float* __restrict__ att,
                                             const float* __restrict__ bias,
                                             float* __restrict__ out,
                                             unsigned short* __restrict__ outb) {
    int n = (blockIdx.x * 256 + threadIdx.x) >> 6;
    int lane = threadIdx.x & 63;
    if (n >= N_NODES) return;
    int start = rowptr[n], end = rowptr[n + 1];
    int grp = lane >> 4, sub = lane & 15;
    int c0 = sub * 8;

    f32x2 xr2[4], a2[4];
    {
        uint4 u = *(const uint4*)&xrh[(size_t)n * 128 + c0];
        unsigned int uu[4] = {u.x, u.y, u.z, u.w};
#pragma unroll
        for (int q = 0; q < 4; ++q) {
            h2v hh = __builtin_bit_cast(h2v, uu[q]);
            xr2[q] = (f32x2){(float)hh.x, (float)hh.y};
        }
#pragma unroll
        for (int q = 0; q < 4; ++q)
            a2[q] = *(const f32x2*)&att[c0 + 2 * q];
    }

    float m = -1e30f, den = 0.f;
    f32x2 acc2[4] = {};

    int e0 = start + grp;
    int sp = esrc[(e0 < end) ? e0 : (end - 1)];
    uint4 u = *(const uint4*)&xlh[(size_t)sp * 128 + c0];

    for (int i = start; i < end; i += 4) {
        bool valid = (i + grp) < end;
        uint4 uc = u;
        int enext = i + 4 + grp;
        if (enext < end) {
            int s2 = esrc[enext];
            u = *(const uint4*)&xlh[(size_t)s2 * 128 + c0];
        }
        unsigned int uu[4] = {uc.x, uc.y, uc.z, uc.w};
        f32x2 c2[4];
#pragma unroll
        for (int q = 0; q < 4; ++q) {
            h2v hh = __builtin_bit_cast(h2v, uu[q]);
            c2[q] = (f32x2){(float)hh.x, (float)hh.y};
        }
        f32x2 tp = {0.f, 0.f};
#pragma unroll
        for (int q = 0; q < 4; ++q) {
            f32x2 v = c2[q] + xr2[q];
            f32x2 lr = __builtin_elementwise_max(v, v * NEG_SLOPE);
            tp = lr * a2[q] + tp;                 // contracts to v_pk_fma_f32
        }
        float t = tp.x + tp.y;
        const int STEPS = (H == 2) ? 3 : 4;       // 8-lane vs 16-lane reduce
#pragma unroll
        for (int k = 0; k < STEPS; ++k)
            t += __shfl_xor(t, 1 << k, 64);
        float sc = valid ? t : -1e38f;

        if (__any(sc > m)) {                      // rare: new running max
            float mn = fmaxf(m, sc);
            float corr = __expf(m - mn);
            float p = __expf(sc - mn);
            m = mn;
            den = fmaf(den, corr, p);
#pragma unroll
            for (int q = 0; q < 4; ++q)
                acc2[q] = acc2[q] * corr + c2[q] * p;
        } else {                                  // common fast path (corr==1)
            float p = __expf(sc - m);
            den += p;
#pragma unroll
            for (int q = 0; q < 4; ++q)
                acc2[q] = c2[q] * p + acc2[q];
        }
    }

    // merge the 4 edge-slot groups (xor 16, then 32)
#pragma unroll
    for (int off = 16; off <= 32; off <<= 1) {
        float mo = __shfl_xor(m, off, 64);
        float deno = __shfl_xor(den, off, 64);
        f32x2 ao[4];
#pragma unroll
        for (int q = 0; q < 4; ++q) {
            ao[q].x = __shfl_xor(acc2[q].x, off, 64);
            ao[q].y = __shfl_xor(acc2[q].y, off, 64);
        }
        float mn = fmaxf(m, mo);
        float cc1 = __expf(m - mn);
        float cc2 = __expf(mo - mn);
        m = mn;
        den = den * cc1 + deno * cc2;
#pragma unroll
        for (int q = 0; q < 4; ++q)
            acc2[q] = acc2[q] * cc1 + ao[q] * cc2;
    }

    if (grp == 0) {
        float inv = 1.f / (den + 1e-16f);
        float o[8];
#pragma unroll
        for (int q = 0; q < 4; ++q) {
            f32x2 bb = *(const f32x2*)&bias[c0 + 2 * q];
            f32x2 vv = acc2[q] * inv + bb;
            o[2 * q]     = (vv.x > 0.f) ? vv.x : (__expf(vv.x) - 1.f);   // ELU
            o[2 * q + 1] = (vv.y > 0.f) ? vv.y : (__expf(vv.y) - 1.f);
        }
        if (BF16OUT) {
            unsigned short hi[8], lo[8];
#pragma unroll
            for (int j = 0; j < 8; ++j) {
                hi[j] = f2bf(o[j]);
                lo[j] = f2bf(o[j] - bf2f(hi[j]));
            }
            *(uint4*)&outb[(size_t)n * 256 + c0] = *(const uint4*)hi;
            *(uint4*)&outb[(size_t)n * 256 + 128 + c0] = *(const uint4*)lo;
        } else {
            *(float4*)&out[(size_t)n * 128 + c0] = make_float4(o[0], o[1], o[2], o[3]);
            *(float4*)&out[(size_t)n * 128 + c0 + 4] = make_float4(o[4], o[5], o[6], o[7]);
        }
    }
}

// ---------------------------------------------------------------- launch
extern "C" void kernel_launch(void* const* d_in, const int* in_sizes, int n_in,
                              void* d_out, int out_size, void* d_ws, size_t ws_size,
                              hipStream_t stream) {
    const float* x    = (const float*)d_in[0];
    const int*   ei   = (const int*)d_in[1];
    const float* Wl1  = (const float*)d_in[2];
    const float* Wr1  = (const float*)d_in[3];
    const float* att1 = (const float*)d_in[4];
    const float* b1   = (const float*)d_in[5];
    const float* Wl2  = (const float*)d_in[6];
    const float* Wr2  = (const float*)d_in[7];
    const float* att2 = (const float*)d_in[8];
    const float* b2   = (const float*)d_in[9];
    const int* srcp = ei;
    const int* dstp = ei + N_EDGES;

    char* ws = (char*)d_ws;
    size_t off = 0;
    auto alloc = [&](size_t bytes) {
        void* p = ws + off;
        off = (off + bytes + 255) & ~(size_t)255;
        return p;
    };
    int*      bcount  = (int*)alloc(NBKT * sizeof(int));
    int*      bbase   = (int*)alloc((NBKT + 1) * sizeof(int));
    unsigned* ebuf    = (unsigned*)alloc((size_t)NBKT * BKT_CAP * sizeof(unsigned));
    int*      rowptr  = (int*)alloc((N_NODES + 1) * sizeof(int));
    int*      esrc    = (int*)alloc((size_t)TOT_E * sizeof(int));
    unsigned short* xp  = (unsigned short*)alloc((size_t)N_NODES * 256 * sizeof(short));
    unsigned short* Bp1 = (unsigned short*)alloc(65536 * sizeof(short));
    unsigned short* Bp2 = (unsigned short*)alloc(65536 * sizeof(short));
    unsigned short* xl  = (unsigned short*)alloc((size_t)N_NODES * 128 * sizeof(short));
    unsigned short* xr  = (unsigned short*)alloc((size_t)N_NODES * 128 * sizeof(short));

    // CSR build: bucketed counting sort, coalesced writes, no global pre-scan
    hipMemsetAsync(bcount, 0, NBKT * sizeof(int), stream);
    kA<<<NCHUNK, 1024, 0, stream>>>(srcp, dstp, bcount, ebuf);
    kScanB<<<1, 256, 0, stream>>>(bcount, bbase);
    kB<<<NBKT, 1024, 0, stream>>>(ebuf, bcount, bbase, rowptr, esrc);

    // weight prep (both layers, one launch)
    k_pack2<<<512, 256, 0, stream>>>(Wl1, Wr1, Wl2, Wr2, Bp1, Bp2);

    int mfma_grid = (N_NODES + 63) / 64;

    // layer 1: heads=2, C=64, concat
    k_mfma_lin<true><<<mfma_grid, 256, 0, stream>>>(x, Bp1, xl, xr, N_NODES);
    k_gat<2, true><<<(N_NODES + 3) / 4, 256, 0, stream>>>(rowptr, esrc, xl, xr, att1, b1,
                                                          nullptr, xp);
    // layer 2: heads=1, C=128, mean over 1 head = identity
    k_mfma_lin<false><<<mfma_grid, 256, 0, stream>>>(xp, Bp2, xl, xr, N_NODES);
    k_gat<1, false><<<(N_NODES + 3) / 4, 256, 0, stream>>>(rowptr, esrc, xl, xr, att2, b2,
                                                           (float*)d_out, nullptr);
}

// Round 9
// 166.838 us; speedup vs baseline: 1.0606x; 1.0606x over previous
//
#include <hip/hip_runtime.h>
#include <hip/hip_bf16.h>

#define N_NODES 50000
#define N_EDGES 800000
#define TOT_E   (N_EDGES + N_NODES)   // edges + self loops = 850000
#define NEG_SLOPE 0.2f
#define NBKT 196         // buckets of 256 nodes: 196*256 = 50176 >= 50000
#define NPB 256          // nodes per bucket
#define BKT_CAP 6144     // max edges per bucket (mean 4352, sd ~64)
#define CHUNK 4096       // edges per block in pass A
#define NCHUNK ((TOT_E + CHUNK - 1) / CHUNK)   // 208

typedef __attribute__((ext_vector_type(8))) short bf16x8;
typedef __attribute__((ext_vector_type(4))) float f32x4;

static __device__ __forceinline__ unsigned short f2bf(float f) {
    unsigned int u = __float_as_uint(f);
    unsigned int r = (u + 0x7FFFu + ((u >> 16) & 1u)) >> 16;   // RNE
    return (unsigned short)r;
}
static __device__ __forceinline__ float bf2f(unsigned short h) {
    return __uint_as_float(((unsigned int)h) << 16);
}
static __device__ __forceinline__ unsigned short f2h(float f) {
    _Float16 h = (_Float16)f;                                   // v_cvt_f16_f32 (RNE)
    return __builtin_bit_cast(unsigned short, h);
}
static __device__ __forceinline__ float h2f(unsigned short u) {
    return (float)__builtin_bit_cast(_Float16, u);
}

// ---------------------------------------------------------------- CSR build
// Pass A: per-block LDS bucket counting-sort; blocks reserve space directly in
// fixed-capacity bucket regions of ebuf (one global atomic per block-bucket).
// packed u32: src[0:16) | local_dst[16:24) | bucket[24:32)
__global__ __launch_bounds__(1024) void kA(const int* __restrict__ srcp,
                                           const int* __restrict__ dstp,
                                           int* __restrict__ bcount,
                                           unsigned* __restrict__ ebuf) {
    __shared__ int h[NBKT];
    __shared__ int lbase[NBKT];
    __shared__ int lcur[NBKT];
    __shared__ int sc[256];
    __shared__ unsigned stage[CHUNK];
    int t = threadIdx.x;
    if (t < NBKT) h[t] = 0;
    __syncthreads();
    int base = blockIdx.x * CHUNK;
    int nloc = min(CHUNK, TOT_E - base);
    for (int i = t; i < nloc; i += 1024) {
        int e = base + i;
        int d = (e < N_EDGES) ? dstp[e] : (e - N_EDGES);
        atomicAdd(&h[d >> 8], 1);
    }
    __syncthreads();
    if (t < NBKT) lbase[t] = h[t] ? atomicAdd(&bcount[t], h[t]) : 0;
    if (t < 256) sc[t] = (t < NBKT) ? h[t] : 0;
    __syncthreads();
    for (int off = 1; off < 256; off <<= 1) {
        int v = (t < 256 && t >= off) ? sc[t - off] : 0;
        __syncthreads();
        if (t < 256) sc[t] += v;
        __syncthreads();
    }
    if (t < NBKT) lcur[t] = sc[t] - h[t];   // exclusive scan: run starts in stage
    __syncthreads();
    for (int i = t; i < nloc; i += 1024) {
        int e = base + i;
        int d = (e < N_EDGES) ? dstp[e] : (e - N_EDGES);
        int s = (e < N_EDGES) ? srcp[e] : (e - N_EDGES);
        int b = d >> 8;
        int p = atomicAdd(&lcur[b], 1);
        stage[p] = (unsigned)s | ((unsigned)(d & 255) << 16) | ((unsigned)b << 24);
    }
    __syncthreads();
    // stage is bucket-sorted: linear read -> contiguous runs into bucket regions
    for (int i = t; i < nloc; i += 1024) {
        unsigned v = stage[i];
        int b = v >> 24;
        int pl = lbase[b] + (i - (lcur[b] - h[b]));
        if (pl < BKT_CAP) ebuf[(size_t)b * BKT_CAP + pl] = v & 0xFFFFFFu;
    }
}

// scan bucket counts -> bbase (exclusive, NBKT+1 entries)
__global__ void kScanB(const int* __restrict__ bcount, int* __restrict__ bbase) {
    __shared__ int s[256];
    int t = threadIdx.x;   // 256 threads
    int own = (t < NBKT) ? bcount[t] : 0;
    s[t] = own;
    __syncthreads();
    for (int off = 1; off < 256; off <<= 1) {
        int v = (t >= off) ? s[t - off] : 0;
        __syncthreads();
        s[t] += v;
        __syncthreads();
    }
    if (t < NBKT) bbase[t] = s[t] - own;
    if (t == NBKT - 1) bbase[NBKT] = s[t];
}

// Pass B: one block per bucket -> exact CSR (rowptr + esrc), all coalesced
__global__ __launch_bounds__(1024) void kB(const unsigned* __restrict__ ebuf,
                                           const int* __restrict__ bcount,
                                           const int* __restrict__ bbase,
                                           int* __restrict__ rowptr,
                                           int* __restrict__ esrc) {
    __shared__ int h[NPB];
    __shared__ int sc[NPB];
    __shared__ int st2[BKT_CAP];
    int b = blockIdx.x;
    int t = threadIdx.x;
    int gb = bbase[b];
    int cnt = min(bcount[b], BKT_CAP);
    const unsigned* eb = ebuf + (size_t)b * BKT_CAP;
    if (t < NPB) h[t] = 0;
    __syncthreads();
    for (int i = t; i < cnt; i += 1024)
        atomicAdd(&h[(eb[i] >> 16) & 255], 1);
    __syncthreads();
    if (t < NPB) sc[t] = h[t];
    __syncthreads();
    for (int off = 1; off < NPB; off <<= 1) {
        int v = (t < NPB && t >= off) ? sc[t - off] : 0;
        __syncthreads();
        if (t < NPB) sc[t] += v;
        __syncthreads();
    }
    if (t < NPB) h[t] = sc[t] - h[t];   // exclusive scan (scatter cursor)
    __syncthreads();
    int node0 = b << 8;
    if (t < NPB && node0 + t < N_NODES) rowptr[node0 + t] = gb + h[t];
    if (b == NBKT - 1 && t == 0) rowptr[N_NODES] = TOT_E;
    for (int i = t; i < cnt; i += 1024) {
        unsigned v = eb[i];
        int p = atomicAdd(&h[(v >> 16) & 255], 1);
        st2[p] = (int)(v & 0xFFFFu);
    }
    __syncthreads();
    for (int i = t; i < cnt; i += 1024) esrc[gb + i] = st2[i];
}

// ------------------------------------------------- weight pack (both layers)
__global__ void k_pack2(const float* __restrict__ Wl1, const float* __restrict__ Wr1,
                        const float* __restrict__ Wl2, const float* __restrict__ Wr2,
                        unsigned short* __restrict__ Bp1, unsigned short* __restrict__ Bp2) {
    int gidx = blockIdx.x * 256 + threadIdx.x;   // 131072 total
    int which = gidx >> 16;
    int idx = gidx & 65535;
    const float* Wa = which ? Wl2 : Wl1;
    const float* Wb = which ? Wr2 : Wr1;
    unsigned short* Bp = which ? Bp2 : Bp1;
    int j = idx & 7, lane = (idx >> 3) & 63, t = idx >> 9;
    int ks = t >> 4, ctg = t & 15;
    int k = (ks * 32 + (lane >> 4) * 8 + j) & 127;
    int n = ctg * 16 + (lane & 15);
    float v = (n < 128) ? Wa[k * 128 + n] : Wb[k * 128 + (n - 128)];
    Bp[idx] = f2bf(v);
}

// ------------------------------------------------- MFMA dual linear -> fp16 out
template <bool F32IN>
__global__ __launch_bounds__(256) void k_mfma_lin(const void* __restrict__ Ain,
                                                  const unsigned short* __restrict__ Bp,
                                                  unsigned short* __restrict__ outA,
                                                  unsigned short* __restrict__ outB, int M) {
    __shared__ unsigned short lds_a[64][264];   // +8 pad
    int tid = threadIdx.x;
    int n0 = blockIdx.x * 64;
    if (F32IN) {
        const float* X = (const float*)Ain;
#pragma unroll
        for (int r = 0; r < 8; ++r) {
            int c = r * 256 + tid;
            int row = c >> 5;
            int col4 = (c & 31) * 4;
            int gr = n0 + row;
            if (gr >= M) gr = M - 1;
            float4 v = *(const float4*)&X[(size_t)gr * 128 + col4];
            float vv[4] = {v.x, v.y, v.z, v.w};
            ushort4 hh, ll;
            unsigned short* hp = &hh.x;
            unsigned short* lp = &ll.x;
#pragma unroll
            for (int q = 0; q < 4; ++q) {
                unsigned short hv = f2bf(vv[q]);
                hp[q] = hv;
                lp[q] = f2bf(vv[q] - bf2f(hv));
            }
            *(ushort4*)&lds_a[row][col4] = hh;
            *(ushort4*)&lds_a[row][128 + col4] = ll;
        }
    } else {
        const unsigned short* Ap = (const unsigned short*)Ain;
#pragma unroll
        for (int r = 0; r < 8; ++r) {
            int c = r * 256 + tid;
            int row = c >> 5;
            int col = (c & 31) * 8;
            int gr = n0 + row;
            if (gr >= M) gr = M - 1;
            float4 v = *(const float4*)&Ap[(size_t)gr * 256 + col];
            *(float4*)&lds_a[row][col] = v;
        }
    }
    __syncthreads();

    int w = tid >> 6, lane = tid & 63;
    int lrow = lane & 15, lhi = lane >> 4;
    f32x4 acc[4][4] = {};
    const bf16x8* Bf = (const bf16x8*)Bp;
#pragma unroll
    for (int ks = 0; ks < 8; ++ks) {
        bf16x8 bfr[4], afr[4];
#pragma unroll
        for (int ct = 0; ct < 4; ++ct)
            bfr[ct] = Bf[(ks * 16 + (w * 4 + ct)) * 64 + lane];
#pragma unroll
        for (int mt = 0; mt < 4; ++mt)
            afr[mt] = *(const bf16x8*)&lds_a[mt * 16 + lrow][ks * 32 + lhi * 8];
#pragma unroll
        for (int mt = 0; mt < 4; ++mt)
#pragma unroll
            for (int ct = 0; ct < 4; ++ct)
                acc[mt][ct] = __builtin_amdgcn_mfma_f32_16x16x32_bf16(
                    afr[mt], bfr[ct], acc[mt][ct], 0, 0, 0);
    }
#pragma unroll
    for (int mt = 0; mt < 4; ++mt) {
        int row0 = n0 + mt * 16 + lhi * 4;
#pragma unroll
        for (int ct = 0; ct < 4; ++ct) {
            int col = w * 64 + ct * 16 + lrow;
            unsigned short* dst = (col < 128) ? outA : outB;   // wave-uniform
            int cc = col & 127;
#pragma unroll
            for (int reg = 0; reg < 4; ++reg) {
                int rg = row0 + reg;
                if (rg < M) dst[(size_t)rg * 128 + cc] = f2h(acc[mt][ct][reg]);
            }
        }
    }
}

// ------------------------------------------------- fused score+softmax+aggregate
// One wave per node; 16 lanes per edge slot, 4 edge slots per wave (R7 proven
// branchless loop). Deeper pipeline: 2-batch row prefetch (u0,u1) + 3-batch
// index prefetch (sC) to cover the esrc->xlh dependent-load chain.
template <int H, bool BF16OUT>
__global__ __launch_bounds__(256) void k_gat(const int* __restrict__ rowptr,
                                             const int* __restrict__ esrc,
                                             const unsigned short* __restrict__ xlh,
                                             const unsigned short* __restrict__ xrh,
                                             const float* __restrict__ att,
                                             const float* __restrict__ bias,
                                             float* __restrict__ out,
                                             unsigned short* __restrict__ outb) {
    int n = (blockIdx.x * 256 + threadIdx.x) >> 6;
    int lane = threadIdx.x & 63;
    if (n >= N_NODES) return;
    int start = rowptr[n], end = rowptr[n + 1];
    int grp = lane >> 4, sub = lane & 15;
    int c0 = sub * 8;

    float xr8[8], a8[8];
    {
        uint4 u = *(const uint4*)&xrh[(size_t)n * 128 + c0];
        unsigned int uu[4] = {u.x, u.y, u.z, u.w};
#pragma unroll
        for (int q = 0; q < 4; ++q) {
            xr8[2 * q]     = h2f((unsigned short)uu[q]);
            xr8[2 * q + 1] = h2f((unsigned short)(uu[q] >> 16));
        }
        float4 av0 = *(const float4*)&att[c0];
        float4 av1 = *(const float4*)&att[c0 + 4];
        a8[0] = av0.x; a8[1] = av0.y; a8[2] = av0.z; a8[3] = av0.w;
        a8[4] = av1.x; a8[5] = av1.y; a8[6] = av1.z; a8[7] = av1.w;
    }

    float m = -1e30f, den = 0.f;
    float acc[8] = {0.f, 0.f, 0.f, 0.f, 0.f, 0.f, 0.f, 0.f};

    // prologue: indices for batches 0,1,2; rows for batches 0,1
    int last = end - 1;
    auto cidx = [&](int e) { return esrc[(e < end) ? e : last]; };
    int sA = cidx(start + grp);
    int sB = cidx(start + 4 + grp);
    int sC = cidx(start + 8 + grp);
    uint4 u0 = *(const uint4*)&xlh[(size_t)sA * 128 + c0];
    uint4 u1 = *(const uint4*)&xlh[(size_t)sB * 128 + c0];

    for (int i = start; i < end; i += 4) {
        bool valid = (i + grp) < end;
        uint4 uc = u0;
        u0 = u1;
        u1 = *(const uint4*)&xlh[(size_t)sC * 128 + c0];   // row for batch b+2
        sC = cidx(i + 12 + grp);                            // index for batch b+3
        unsigned int uu[4] = {uc.x, uc.y, uc.z, uc.w};
        float c[8];
#pragma unroll
        for (int q = 0; q < 4; ++q) {
            c[2 * q]     = h2f((unsigned short)uu[q]);
            c[2 * q + 1] = h2f((unsigned short)(uu[q] >> 16));
        }
        float t = 0.f;
#pragma unroll
        for (int j = 0; j < 8; ++j) {
            float v = c[j] + xr8[j];
            v = fmaxf(v, NEG_SLOPE * v);
            t = fmaf(v, a8[j], t);
        }
        const int STEPS = (H == 2) ? 3 : 4;
#pragma unroll
        for (int k = 0; k < STEPS; ++k)
            t += __shfl_xor(t, 1 << k, 64);
        float sc = valid ? t : -1e38f;

        float mn = fmaxf(m, sc);
        float corr = __expf(m - mn);
        float p = __expf(sc - mn);
        m = mn;
        den = fmaf(den, corr, p);
#pragma unroll
        for (int j = 0; j < 8; ++j)
            acc[j] = fmaf(acc[j], corr, p * c[j]);
    }

    // merge the 4 edge-slot groups (xor 16, then 32)
#pragma unroll
    for (int off = 16; off <= 32; off <<= 1) {
        float mo = __shfl_xor(m, off, 64);
        float deno = __shfl_xor(den, off, 64);
        float ao[8];
#pragma unroll
        for (int j = 0; j < 8; ++j) ao[j] = __shfl_xor(acc[j], off, 64);
        float mn = fmaxf(m, mo);
        float c1 = __expf(m - mn);
        float c2 = __expf(mo - mn);
        m = mn;
        den = den * c1 + deno * c2;
#pragma unroll
        for (int j = 0; j < 8; ++j)
            acc[j] = fmaf(acc[j], c1, ao[j] * c2);
    }

    if (grp == 0) {
        float inv = 1.f / (den + 1e-16f);
        float o[8];
        float4 bv0 = *(const float4*)&bias[c0];
        float4 bv1 = *(const float4*)&bias[c0 + 4];
        float bb[8] = {bv0.x, bv0.y, bv0.z, bv0.w, bv1.x, bv1.y, bv1.z, bv1.w};
#pragma unroll
        for (int j = 0; j < 8; ++j) {
            float v = fmaf(acc[j], inv, bb[j]);
            o[j] = (v > 0.f) ? v : (__expf(v) - 1.f);   // ELU
        }
        if (BF16OUT) {
            unsigned short hi[8], lo[8];
#pragma unroll
            for (int j = 0; j < 8; ++j) {
                hi[j] = f2bf(o[j]);
                lo[j] = f2bf(o[j] - bf2f(hi[j]));
            }
            *(uint4*)&outb[(size_t)n * 256 + c0] = *(const uint4*)hi;
            *(uint4*)&outb[(size_t)n * 256 + 128 + c0] = *(const uint4*)lo;
        } else {
            *(float4*)&out[(size_t)n * 128 + c0] = make_float4(o[0], o[1], o[2], o[3]);
            *(float4*)&out[(size_t)n * 128 + c0 + 4] = make_float4(o[4], o[5], o[6], o[7]);
        }
    }
}

// ---------------------------------------------------------------- launch
extern "C" void kernel_launch(void* const* d_in, const int* in_sizes, int n_in,
                              void* d_out, int out_size, void* d_ws, size_t ws_size,
                              hipStream_t stream) {
    const float* x    = (const float*)d_in[0];
    const int*   ei   = (const int*)d_in[1];
    const float* Wl1  = (const float*)d_in[2];
    const float* Wr1  = (const float*)d_in[3];
    const float* att1 = (const float*)d_in[4];
    const float* b1   = (const float*)d_in[5];
    const float* Wl2  = (const float*)d_in[6];
    const float* Wr2  = (const float*)d_in[7];
    const float* att2 = (const float*)d_in[8];
    const float* b2   = (const float*)d_in[9];
    const int* srcp = ei;
    const int* dstp = ei + N_EDGES;

    char* ws = (char*)d_ws;
    size_t off = 0;
    auto alloc = [&](size_t bytes) {
        void* p = ws + off;
        off = (off + bytes + 255) & ~(size_t)255;
        return p;
    };
    int*      bcount  = (int*)alloc(NBKT * sizeof(int));
    int*      bbase   = (int*)alloc((NBKT + 1) * sizeof(int));
    unsigned* ebuf    = (unsigned*)alloc((size_t)NBKT * BKT_CAP * sizeof(unsigned));
    int*      rowptr  = (int*)alloc((N_NODES + 1) * sizeof(int));
    int*      esrc    = (int*)alloc((size_t)TOT_E * sizeof(int));
    unsigned short* xp  = (unsigned short*)alloc((size_t)N_NODES * 256 * sizeof(short));
    unsigned short* Bp1 = (unsigned short*)alloc(65536 * sizeof(short));
    unsigned short* Bp2 = (unsigned short*)alloc(65536 * sizeof(short));
    unsigned short* xl  = (unsigned short*)alloc((size_t)N_NODES * 128 * sizeof(short));
    unsigned short* xr  = (unsigned short*)alloc((size_t)N_NODES * 128 * sizeof(short));

    // CSR build: bucketed counting sort, coalesced writes, no global pre-scan
    hipMemsetAsync(bcount, 0, NBKT * sizeof(int), stream);
    kA<<<NCHUNK, 1024, 0, stream>>>(srcp, dstp, bcount, ebuf);
    kScanB<<<1, 256, 0, stream>>>(bcount, bbase);
    kB<<<NBKT, 1024, 0, stream>>>(ebuf, bcount, bbase, rowptr, esrc);

    // weight prep (both layers, one launch)
    k_pack2<<<512, 256, 0, stream>>>(Wl1, Wr1, Wl2, Wr2, Bp1, Bp2);

    int mfma_grid = (N_NODES + 63) / 64;

    // layer 1: heads=2, C=64, concat
    k_mfma_lin<true><<<mfma_grid, 256, 0, stream>>>(x, Bp1, xl, xr, N_NODES);
    k_gat<2, true><<<(N_NODES + 3) / 4, 256, 0, stream>>>(rowptr, esrc, xl, xr, att1, b1,
                                                          nullptr, xp);
    // layer 2: heads=1, C=128, mean over 1 head = identity
    k_mfma_lin<false><<<mfma_grid, 256, 0, stream>>>(xp, Bp2, xl, xr, N_NODES);
    k_gat<1, false><<<(N_NODES + 3) / 4, 256, 0, stream>>>(rowptr, esrc, xl, xr, att2, b2,
                                                           (float*)d_out, nullptr);
}